// Round 5
// baseline (1727.717 us; speedup 1.0000x reference)
//
#include <hip/hip_runtime.h>
#include <hip/hip_bf16.h>
#include <math.h>

#define NN 3
#define BB 4
#define CC 256
#define C2 512
#define HH 40
#define WW 40
#define PP 1600
#define NBB 12                  // NN*BB
#define NODESZ (NBB*CC*PP)      // 4,915,200
#define TO 16                   // theta: output channels per block
#define PAD 1764                // 42*42 padded pixels

typedef short short8 __attribute__((ext_vector_type(8)));
typedef float f32x4 __attribute__((ext_vector_type(4)));
typedef unsigned short ushort_t;
typedef unsigned int uint_t;

__device__ __forceinline__ ushort_t f2bf(float x) {
  union { float f; uint_t u; } v; v.f = x;
  uint_t r = v.u + 0x7fff + ((v.u >> 16) & 1);
  return (ushort_t)(r >> 16);
}

__device__ __forceinline__ void async_ld16(const ushort_t* g, ushort_t* l) {
  __builtin_amdgcn_global_load_lds(
      (const __attribute__((address_space(1))) uint_t*)g,
      (__attribute__((address_space(3))) uint_t*)l, 16, 0, 0);
}

__global__ void k_copy(const float* __restrict__ in, float* __restrict__ out) {
  int i = blockIdx.x * 256 + threadIdx.x;
  out[i] = in[i];
}

// th_t[nb][p][c] (bf16) = tb[o] + sum_c tw[o,c] * nodes[nb,c,p]
__global__ void k_theta(const float* __restrict__ nodes, const float* __restrict__ tw,
                        const float* __restrict__ tb, ushort_t* __restrict__ th_t) {
  __shared__ float w[TO * CC];
  int t = threadIdx.x;
  int nb = blockIdx.y / (CC / TO);
  int o0 = (blockIdx.y % (CC / TO)) * TO;
  for (int i = t; i < TO * CC; i += 320) w[i] = tw[(o0 + (i >> 8)) * CC + (i & 255)];
  __syncthreads();
  int p = blockIdx.x * 320 + t;
  const float* src = nodes + nb * CC * PP + p;
  float acc[TO];
#pragma unroll
  for (int o = 0; o < TO; ++o) acc[o] = tb[o0 + o];
  for (int c = 0; c < CC; c += 4) {
    float v0 = src[c * PP], v1 = src[(c + 1) * PP], v2 = src[(c + 2) * PP], v3 = src[(c + 3) * PP];
#pragma unroll
    for (int o = 0; o < TO; ++o) {
      const float4 ww = *(const float4*)(w + o * CC + c);
      acc[o] += ww.x * v0 + ww.y * v1 + ww.z * v2 + ww.w * v3;
    }
  }
  size_t base = ((size_t)nb * PP + p) * CC + o0;
#pragma unroll
  for (int o = 0; o < TO; o += 2) {
    uint_t lo = f2bf(acc[o]), hi = f2bf(acc[o + 1]);
    *(uint_t*)&th_t[base + o] = lo | (hi << 16);
  }
}

// nodes [12][256][1600] fp32 -> ejf frag-major bf16:
// ejf[nb][T][ks][f][lane(quad,l16)][j] = nodes[nb][32ks + quad*8 + j][32T + 16f + l16]
// i.e. each (T,ks,f) S-GEMM B-fragment is a contiguous 1KB block, one fully
// coalesced global_load_dwordx4 per fragment in k_attn_mfma.
__global__ void k_to_ejf(const float* __restrict__ src, ushort_t* __restrict__ ejf) {
  __shared__ float tile[32][33];
  int nb = blockIdx.z;
  int ks = blockIdx.y;                  // c-chunk of 32
  int T = blockIdx.x;                   // q-chunk of 32
  int c0 = ks * 32, q0 = T * 32;
  int tx = threadIdx.x & 31, ty = threadIdx.x >> 5;
#pragma unroll
  for (int i = 0; i < 4; ++i)
    tile[ty + 8 * i][tx] = src[((size_t)nb * CC + c0 + ty + 8 * i) * PP + q0 + tx];
  __syncthreads();
  // 256 threads write 8B each -> 2KB contiguous per tile
  int id = threadIdx.x >> 1;            // chunk 0..127
  int f = id >> 6, l = id & 63;
  int quad = l >> 4, l16 = l & 15;
  int jb = (threadIdx.x & 1) * 4;
  float v0 = tile[quad * 8 + jb + 0][f * 16 + l16];
  float v1 = tile[quad * 8 + jb + 1][f * 16 + l16];
  float v2 = tile[quad * 8 + jb + 2][f * 16 + l16];
  float v3 = tile[quad * 8 + jb + 3][f * 16 + l16];
  uint2 u;
  u.x = (uint_t)f2bf(v0) | ((uint_t)f2bf(v1) << 16);
  u.y = (uint_t)f2bf(v2) | ((uint_t)f2bf(v3) << 16);
  *(uint2*)(ejf + ((((size_t)nb * 50 + T) * 8 + ks) * 2 + f) * 512 + l * 8 + jb) = u;
}

// vf frag-major bf16: vf[eb][T][nt][lane(quad,l16)][j]
//   = nodes[recv][c][p] + nodes[send][c][p],  c = 16nt + l16, p = 32T + quad*8 + j
// Each (T,nt) PV B-fragment = contiguous 1KB, one coalesced load in attn.
__global__ void k_prep_vf(const float* __restrict__ nodes, ushort_t* __restrict__ vf) {
  int T = blockIdx.x;                   // 0..49
  int eb = blockIdx.y;                  // 0..23
  int e = eb >> 2, b = eb & 3;
  int n = e >> 1, jidx = e & 1;
  int js = jidx + (jidx >= n ? 1 : 0);
  const float* s0 = nodes + (size_t)(n * BB + b) * CC * PP;
  const float* s1 = nodes + (size_t)(js * BB + b) * CC * PP;
  ushort_t* dst = vf + ((size_t)eb * 50 + T) * 8192;
  int t = threadIdx.x;
#pragma unroll
  for (int k = 0; k < 4; ++k) {
    int cid = t + 256 * k;              // 0..1023 (16 nt x 64 lanes)
    int nt = cid >> 6, l = cid & 63;
    int quad = l >> 4, l16 = l & 15;
    int c = 16 * nt + l16;
    int p = 32 * T + quad * 8;
    const float4* a0 = (const float4*)(s0 + (size_t)c * PP + p);
    const float4* a1 = (const float4*)(s1 + (size_t)c * PP + p);
    float4 x0 = a0[0], x1 = a0[1];
    float4 y0 = a1[0], y1 = a1[1];
    short8 o;
    o[0] = (short)f2bf(x0.x + y0.x); o[1] = (short)f2bf(x0.y + y0.y);
    o[2] = (short)f2bf(x0.z + y0.z); o[3] = (short)f2bf(x0.w + y0.w);
    o[4] = (short)f2bf(x1.x + y1.x); o[5] = (short)f2bf(x1.y + y1.y);
    o[6] = (short)f2bf(x1.z + y1.z); o[7] = (short)f2bf(x1.w + y1.w);
    *(short8*)(dst + (size_t)cid * 8) = o;
  }
}

// Barrier-free flash attention.
//  R4 post-mortem: occupancy fix landed (24%) but dur barely moved -> the
//  limiter is the 2-barrier/iteration lockstep schedule itself (exposed async
//  latency at A, all waves stalled together, no cross-iteration overlap).
//  This version removes ALL __syncthreads from the loop:
//   - S-GEMM B-frags: direct coalesced 1KB loads from frag-major ejf (no Ej
//     LDS, no staging). Both waves read the same stream -> L1 dedup.
//   - wave owns 16 p-rows AND all 256 channels: softmax row (quad*4+r) ==
//     MFMA C-row, so max/alpha/L never leave the lane. No Al/Linv LDS.
//   - P transpose via wave-private Sp (ds_write -> lgkmcnt -> ds_read).
//   - PV B-frags: direct coalesced 1KB loads from frag-major vf.
//  With no barriers the compiler is free to hoist next-iteration loads over
//  softmax/PV; cross-iteration dep is only the O accumulate.
//  launch_bounds(128,3): total reg cap 170 vs ~150 live (O 64 + Ath 32 +
//  state ~20 + load windows) -> 3 waves/SIMD, 6 blocks/CU, grid 1200 in one
//  round. (R2 lesson: never cap below the live set.)
__global__ __launch_bounds__(128, 3) void k_attn_mfma(
    const ushort_t* __restrict__ ejf,   // [12][50][8][2][512] frag-major
    const ushort_t* __restrict__ th_t,  // [12][1600][256]
    const ushort_t* __restrict__ vf,    // [24][50][16][512] frag-major
    float* __restrict__ agg_t)          // [2][12][1600][256]
{
  __shared__ ushort_t Sp[2][16 * 40];   // wave-private P-transpose scratch

  const int t = threadIdx.x;
  const int w = t >> 6;                 // 0..1
  const int l = t & 63;
  const int quad = l >> 4;
  const int l16 = l & 15;
  const int p0 = blockIdx.x * 32 + 16 * w;   // this wave's 16 p-rows
  const int nb = blockIdx.y;
  const int jidx = blockIdx.z;
  const int n = nb >> 2, b = nb & 3;
  const int e = n * 2 + jidx;
  const int js = jidx + (jidx >= n ? 1 : 0);
  const int nbj = js * BB + b;          // source node-batch of ej
  const int eb = e * BB + b;

  const ushort_t* ejbase = ejf + (size_t)nbj * 50 * 8192;
  const ushort_t* vbase  = vf + (size_t)eb * 50 * 8192;
  ushort_t* sp = &Sp[w][0];

  // resident A-frags of th for rows p0+l16
  short8 Ath[8];
  {
    const ushort_t* arow = th_t + ((size_t)nb * PP + p0 + l16) * CC + quad * 8;
#pragma unroll
    for (int ks = 0; ks < 8; ++ks) Ath[ks] = *(const short8*)(arow + ks * 32);
  }

  float M[4], L[4];
#pragma unroll
  for (int r = 0; r < 4; ++r) { M[r] = -3.0e38f; L[r] = 0.f; }

  f32x4 O[16];
#pragma unroll
  for (int nt = 0; nt < 16; ++nt)
#pragma unroll
    for (int r = 0; r < 4; ++r) O[nt][r] = 0.f;

  for (int T = 0; T < 50; ++T) {
    const ushort_t* et = ejbase + T * 8192;
    const ushort_t* vt = vbase + T * 8192;
    // ---- S-GEMM: 16 coalesced B-frag loads, 2 interleaved 8-chains ----
    f32x4 S0, S1;
#pragma unroll
    for (int r = 0; r < 4; ++r) { S0[r] = 0.f; S1[r] = 0.f; }
#pragma unroll
    for (int ks = 0; ks < 8; ++ks) {
      short8 b0 = *(const short8*)(et + ks * 1024 + l * 8);
      short8 b1 = *(const short8*)(et + ks * 1024 + 512 + l * 8);
      S0 = __builtin_amdgcn_mfma_f32_16x16x32_bf16(Ath[ks], b0, S0, 0, 0, 0);
      S1 = __builtin_amdgcn_mfma_f32_16x16x32_bf16(Ath[ks], b1, S1, 0, 0, 0);
    }
    // ---- in-register online softmax; row = quad*4 + r (matches O rows) ----
    float al[4];
#pragma unroll
    for (int r = 0; r < 4; ++r) {
      float m = fmaxf(S0[r], S1[r]);
      m = fmaxf(m, __shfl_xor(m, 1));
      m = fmaxf(m, __shfl_xor(m, 2));
      m = fmaxf(m, __shfl_xor(m, 4));
      m = fmaxf(m, __shfl_xor(m, 8));
      float Mn = fmaxf(M[r], m);
      al[r] = __expf(M[r] - Mn);
      float e0 = __expf(S0[r] - Mn), e1 = __expf(S1[r] - Mn);
      float s = e0 + e1;
      s += __shfl_xor(s, 1);
      s += __shfl_xor(s, 2);
      s += __shfl_xor(s, 4);
      s += __shfl_xor(s, 8);
      L[r] = L[r] * al[r] + s;
      M[r] = Mn;
      sp[(quad * 4 + r) * 40 + l16] = f2bf(e0);
      sp[(quad * 4 + r) * 40 + 16 + l16] = f2bf(e1);
    }
    // wave-private transpose readback (compiler inserts lgkmcnt; no barrier)
    short8 Ap = *(const short8*)(sp + l16 * 40 + quad * 8);
    // ---- rescale O by in-register alpha ----
#pragma unroll
    for (int nt = 0; nt < 16; ++nt)
#pragma unroll
      for (int r = 0; r < 4; ++r) O[nt][r] *= al[r];
    // ---- PV: 16 coalesced V-frag loads, 16 independent MFMAs ----
#pragma unroll
    for (int nt = 0; nt < 16; ++nt) {
      short8 bv = *(const short8*)(vt + nt * 512 + l * 8);
      O[nt] = __builtin_amdgcn_mfma_f32_16x16x32_bf16(Ap, bv, O[nt], 0, 0, 0);
    }
  }
  // ---- epilogue: L is lane-resident for this lane's rows ----
  float inv[4];
#pragma unroll
  for (int r = 0; r < 4; ++r) inv[r] = 1.f / L[r];
  float* ao = agg_t + (((size_t)jidx * NBB + nb) * PP + p0) * CC;
#pragma unroll
  for (int nt = 0; nt < 16; ++nt)
#pragma unroll
    for (int r = 0; r < 4; ++r)
      ao[(quad * 4 + r) * CC + 16 * nt + l16] = O[nt][r] * inv[r];
}

// ---- conv prep ----

// reorder conv weights [M][512][3][3] fp32 -> [M][9][512] bf16
__global__ void k_wrep(const float* __restrict__ w, ushort_t* __restrict__ wr) {
  int i = blockIdx.x * 256 + threadIdx.x;   // M*9*512
  int ci = i & 511;
  int rest = i >> 9;                        // co*9 + tap
  int tp = rest % 9, co = rest / 9;
  wr[i] = f2bf(w[((size_t)co * 512 + ci) * 9 + tp]);
}

__global__ void k_pad_zero(ushort_t* __restrict__ xpad) {
  int i = blockIdx.x * 256 + threadIdx.x;   // 12*1764*512
  xpad[i] = 0;
}

// interior rows, ch 0..255 <- agg_t[0]+agg_t[1]  (both already [px][c])
__global__ void k_pad_agg(const float* __restrict__ agg_t, ushort_t* __restrict__ xpad) {
  int i = blockIdx.x * 256 + threadIdx.x;   // 12*1600*256
  int c = i & 255;
  int rest = i >> 8;
  int px = rest % PP, nb = rest / PP;
  int y = px / 40, x = px - y * 40;
  size_t src = ((size_t)nb * PP + px) * CC + c;
  float v = agg_t[src] + agg_t[(size_t)NBB * PP * CC + src];
  xpad[((size_t)nb * PAD + (y + 1) * 42 + (x + 1)) * C2 + c] = f2bf(v);
}

// interior rows, ch 256..511 <- transpose of srcA [nb][256][1600]
// MODE 0: val = h[c][px];  MODE 1: val = h[c][px] * r[c][px]
template <int MODE>
__global__ void k_pad_tr(const float* __restrict__ srcA, const float* __restrict__ srcB,
                         ushort_t* __restrict__ xpad) {
  __shared__ float tile[32][33];
  int nb = blockIdx.z;
  int c0 = blockIdx.y * 32;
  int pp0 = blockIdx.x * 32;
  int tx = threadIdx.x & 31, ty = threadIdx.x >> 5;
#pragma unroll
  for (int i = 0; i < 4; ++i) {
    int c = c0 + ty + 8 * i;
    float v = srcA[((size_t)nb * CC + c) * PP + pp0 + tx];
    if (MODE == 1) v *= srcB[((size_t)nb * C2 + c) * PP + pp0 + tx];  // r-gate
    tile[ty + 8 * i][tx] = v;
  }
  __syncthreads();
#pragma unroll
  for (int i = 0; i < 4; ++i) {
    int px = pp0 + ty + 8 * i;
    int y = px / 40, x = px - y * 40;
    xpad[((size_t)nb * PAD + (y + 1) * 42 + (x + 1)) * C2 + CC + c0 + tx] =
        f2bf(tile[tx][ty + 8 * i]);
  }
}

// Implicit-GEMM conv3x3, M=co, N=px(1600), K=9 taps x 512 ci.
// Block: 128co x 128px, 4 waves (2x2), each 64x64 (4x4 16x16x32 frags).
// ACT 0: out = sigmoid(acc+bias) -> gates [nb][512][1600]
// ACT 1: v = tanh(acc+bias); z = zsrc[256+co]; out(nodes) = (1-z)h + z*v
template <int ACT>
__global__ __launch_bounds__(256) void k_conv_mfma(
    const ushort_t* __restrict__ xpad,   // [12][1764][512]
    const ushort_t* __restrict__ wr,     // [M][9*512]
    const float* __restrict__ bias,      // [M]
    const float* __restrict__ zsrc,      // gates (ACT1)
    float* __restrict__ out)
{
  __shared__ ushort_t Asm[128 * 32];
  __shared__ ushort_t Bsm[128 * 32];
  const int t = threadIdx.x;
  const int w = t >> 6, l = t & 63, quad = l >> 4, l16 = l & 15;
  const int nb = blockIdx.z;
  const int m0 = blockIdx.y * 128;
  const int px0 = blockIdx.x * 128;
  const int wm = (w >> 1) * 64, wn = (w & 1) * 64;

  // --- staging source setup (lane l covers rows 32w + l/4 and +16) ---
  const int lr = l >> 2;
  const int swf = (lr ^ (lr >> 2)) & 3;          // fill-side XOR swizzle
  const int lk = ((l & 3) ^ swf) * 8;            // k-part (shorts)
  const ushort_t* wsrc = wr + (size_t)(m0 + 32 * w + lr) * 4608 + lk;
  int pxa = px0 + 32 * w + lr;      if (pxa > 1599) pxa = 1599;
  int pxb = pxa + 16;               if (pxb > 1599) pxb = 1599;
  {
    int d = px0 + 32 * w + 16 + lr; if (d <= 1599) pxb = d;
  }
  const int ya = pxa / 40, xa = pxa - ya * 40;
  const int yb = pxb / 40, xb = pxb - yb * 40;
  const ushort_t* bsrc_a = xpad + ((size_t)nb * PAD + ya * 42 + xa) * C2 + lk;
  const ushort_t* bsrc_b = xpad + ((size_t)nb * PAD + yb * 42 + xb) * C2 + lk;
  ushort_t* Ad0 = Asm + w * 1024;   // wave-uniform LDS base; HW adds lane*16B
  ushort_t* Ad1 = Asm + w * 1024 + 512;
  ushort_t* Bd0 = Bsm + w * 1024;
  ushort_t* Bd1 = Bsm + w * 1024 + 512;

  // --- frag-read swizzle (row&15 == l16 on both A and B) ---
  const int swr = (l16 ^ (l16 >> 2)) & 3;
  const int fk = ((quad ^ swr) * 8);

  f32x4 acc[4][4];
#pragma unroll
  for (int mt = 0; mt < 4; ++mt)
#pragma unroll
    for (int nt = 0; nt < 4; ++nt)
#pragma unroll
      for (int r = 0; r < 4; ++r) acc[mt][nt][r] = 0.f;

  for (int tap = 0; tap < 9; ++tap) {
    const int ky = tap / 3, kx = tap - ky * 3;
    const int boff = (ky * 42 + kx) * C2;
    const ushort_t* wtap = wsrc + tap * 512;
#pragma unroll 1
    for (int c0 = 0; c0 < 512; c0 += 32) {
      __syncthreads();
      async_ld16(wtap + c0, Ad0);
      async_ld16(wtap + 16 * 4608 + c0, Ad1);
      async_ld16(bsrc_a + boff + c0, Bd0);
      async_ld16(bsrc_b + boff + c0, Bd1);
      __syncthreads();
      short8 Af[4], Bf[4];
#pragma unroll
      for (int mt = 0; mt < 4; ++mt)
        Af[mt] = *(const short8*)(Asm + (wm + mt * 16 + l16) * 32 + fk);
#pragma unroll
      for (int nt = 0; nt < 4; ++nt)
        Bf[nt] = *(const short8*)(Bsm + (wn + nt * 16 + l16) * 32 + fk);
#pragma unroll
      for (int mt = 0; mt < 4; ++mt)
#pragma unroll
        for (int nt = 0; nt < 4; ++nt)
          acc[mt][nt] = __builtin_amdgcn_mfma_f32_16x16x32_bf16(Af[mt], Bf[nt], acc[mt][nt], 0, 0, 0);
    }
  }

  // --- epilogue ---
#pragma unroll
  for (int mt = 0; mt < 4; ++mt) {
#pragma unroll
    for (int r = 0; r < 4; ++r) {
      int co = m0 + wm + mt * 16 + quad * 4 + r;
      float bv = bias[co];
#pragma unroll
      for (int nt = 0; nt < 4; ++nt) {
        int px = px0 + wn + nt * 16 + l16;
        if (px >= PP) continue;
        float v = acc[mt][nt][r] + bv;
        if (ACT == 0) {
          out[((size_t)nb * C2 + co) * PP + px] = 1.f / (1.f + __expf(-v));
        } else {
          v = tanhf(v);
          float z = zsrc[((size_t)nb * C2 + CC + co) * PP + px];
          float* hp = out + ((size_t)nb * CC + co) * PP + px;
          float h = *hp;
          *hp = (1.f - z) * h + z * v;
        }
      }
    }
  }
}

extern "C" void kernel_launch(void* const* d_in, const int* in_sizes, int n_in,
                              void* d_out, int out_size, void* d_ws, size_t ws_size,
                              hipStream_t stream) {
  const float* nodes_in = (const float*)d_in[0];
  const float* tw = (const float*)d_in[1];
  const float* tb = (const float*)d_in[2];
  const float* gw = (const float*)d_in[3];
  const float* gb = (const float*)d_in[4];
  const float* cw = (const float*)d_in[5];
  const float* cb = (const float*)d_in[6];

  float* nodes = (float*)d_out;                      // fp32 state [12][256][1600]
  char* ws = (char*)d_ws;
  // ---- layout (ws >= 98.3 MB) ----
  // attn phase: R0 ejf 9.83 | R1 th_t 9.83 | R2 vf 19.66 | R3 agg_t 39.32
  // conv phase: R1+R2 xh_pad 21.68 | R3 gates 39.32
  // persistent:  78.64.. w_g_r 4.72 | 83.36.. w_c_r 2.36   (pass-invariant)
  ushort_t* ejf   = (ushort_t*)ws;
  ushort_t* th_t  = (ushort_t*)(ws + 9830400);
  ushort_t* vf    = (ushort_t*)(ws + 19660800);
  float*    agg_t = (float*)(ws + 39321600);
  ushort_t* xh_pad = (ushort_t*)(ws + 9830400);      // 12*1764*512*2 = 21,676,032
  float*    gates = (float*)(ws + 39321600);
  ushort_t* w_g_r = (ushort_t*)(ws + 78643200);      // 4,718,592 B
  ushort_t* w_c_r = (ushort_t*)(ws + 83361792);      // 2,359,296 B (ends 85.7 MB)

  k_copy<<<NODESZ / 256, 256, 0, stream>>>(nodes_in, nodes);
  k_wrep<<<(C2 * 9 * C2) / 256, 256, 0, stream>>>(gw, w_g_r);
  k_wrep<<<(CC * 9 * C2) / 256, 256, 0, stream>>>(cw, w_c_r);
  for (int pass = 0; pass < 2; ++pass) {
    // ---- attention ----
    k_theta<<<dim3(5, NBB * (CC / TO)), 320, 0, stream>>>(nodes, tw, tb, th_t);
    k_to_ejf<<<dim3(50, 8, NBB), 256, 0, stream>>>(nodes, ejf);
    k_prep_vf<<<dim3(50, 24), 256, 0, stream>>>(nodes, vf);
    k_attn_mfma<<<dim3(50, NBB, 2), 128, 0, stream>>>(ejf, th_t, vf, agg_t);
    // ---- conv prep (attn scratch now dead) ----
    k_pad_zero<<<(NBB * PAD * C2) / 256, 256, 0, stream>>>(xh_pad);
    k_pad_agg<<<(NBB * PP * CC) / 256, 256, 0, stream>>>(agg_t, xh_pad);
    k_pad_tr<0><<<dim3(50, 8, NBB), 256, 0, stream>>>(nodes, nullptr, xh_pad);
    // ---- gates conv ----
    k_conv_mfma<0><<<dim3(13, 4, NBB), 256, 0, stream>>>(xh_pad, w_g_r, gb, nullptr, gates);
    // ---- r*h into xh_pad high channels ----
    k_pad_tr<1><<<dim3(50, 8, NBB), 256, 0, stream>>>(nodes, gates, xh_pad);
    // ---- cand conv + fused GRU update ----
    k_conv_mfma<1><<<dim3(13, 2, NBB), 256, 0, stream>>>(xh_pad, w_c_r, cb, gates, nodes);
  }
}

// Round 6
// 1106.711 us; speedup vs baseline: 1.5611x; 1.5611x over previous
//
#include <hip/hip_runtime.h>
#include <hip/hip_bf16.h>
#include <math.h>

#define NN 3
#define BB 4
#define CC 256
#define C2 512
#define HH 40
#define WW 40
#define PP 1600
#define NBB 12                  // NN*BB
#define NODESZ (NBB*CC*PP)      // 4,915,200
#define TO 16                   // theta: output channels per block
#define PAD 1764                // 42*42 padded pixels

typedef short short8 __attribute__((ext_vector_type(8)));
typedef float f32x4 __attribute__((ext_vector_type(4)));
typedef unsigned short ushort_t;
typedef unsigned int uint_t;

__device__ __forceinline__ ushort_t f2bf(float x) {
  union { float f; uint_t u; } v; v.f = x;
  uint_t r = v.u + 0x7fff + ((v.u >> 16) & 1);
  return (ushort_t)(r >> 16);
}

__device__ __forceinline__ void async_ld16(const ushort_t* g, ushort_t* l) {
  __builtin_amdgcn_global_load_lds(
      (const __attribute__((address_space(1))) uint_t*)g,
      (__attribute__((address_space(3))) uint_t*)l, 16, 0, 0);
}

__global__ void k_copy(const float* __restrict__ in, float* __restrict__ out) {
  int i = blockIdx.x * 256 + threadIdx.x;
  out[i] = in[i];
}

// th_t[nb][p][c] (bf16) = tb[o] + sum_c tw[o,c] * nodes[nb,c,p]
__global__ void k_theta(const float* __restrict__ nodes, const float* __restrict__ tw,
                        const float* __restrict__ tb, ushort_t* __restrict__ th_t) {
  __shared__ float w[TO * CC];
  int t = threadIdx.x;
  int nb = blockIdx.y / (CC / TO);
  int o0 = (blockIdx.y % (CC / TO)) * TO;
  for (int i = t; i < TO * CC; i += 320) w[i] = tw[(o0 + (i >> 8)) * CC + (i & 255)];
  __syncthreads();
  int p = blockIdx.x * 320 + t;
  const float* src = nodes + nb * CC * PP + p;
  float acc[TO];
#pragma unroll
  for (int o = 0; o < TO; ++o) acc[o] = tb[o0 + o];
  for (int c = 0; c < CC; c += 4) {
    float v0 = src[c * PP], v1 = src[(c + 1) * PP], v2 = src[(c + 2) * PP], v3 = src[(c + 3) * PP];
#pragma unroll
    for (int o = 0; o < TO; ++o) {
      const float4 ww = *(const float4*)(w + o * CC + c);
      acc[o] += ww.x * v0 + ww.y * v1 + ww.z * v2 + ww.w * v3;
    }
  }
  size_t base = ((size_t)nb * PP + p) * CC + o0;
#pragma unroll
  for (int o = 0; o < TO; o += 2) {
    uint_t lo = f2bf(acc[o]), hi = f2bf(acc[o + 1]);
    *(uint_t*)&th_t[base + o] = lo | (hi << 16);
  }
}

// nodes [12][256][1600] fp32 -> nodes_bf_t [12][1600][256] bf16 (transpose),
// with 16B-chunk XOR swizzle within each row: c' = c ^ ((q&7)<<3).
// (Consumed only by k_attn_mfma, which un-XORs on its LDS frag reads.)
__global__ void k_to_bf_t(const float* __restrict__ src, ushort_t* __restrict__ dst) {
  __shared__ float tile[32][33];
  int nb = blockIdx.z;
  int c0 = blockIdx.y * 32;
  int pp0 = blockIdx.x * 32;
  int tx = threadIdx.x & 31, ty = threadIdx.x >> 5;
#pragma unroll
  for (int i = 0; i < 4; ++i)
    tile[ty + 8 * i][tx] = src[((size_t)nb * CC + c0 + ty + 8 * i) * PP + pp0 + tx];
  __syncthreads();
#pragma unroll
  for (int i = 0; i < 4; ++i) {
    int q = pp0 + ty + 8 * i;
    int c = c0 + tx;
    int cs = c ^ ((q & 7) << 3);
    dst[((size_t)nb * PP + q) * CC + cs] = f2bf(tile[tx][ty + 8 * i]);
  }
}

// vf frag-major bf16: vf[eb][T][nt][lane(quad,l16)][j]
//   = nodes[recv][c][p] + nodes[send][c][p],  c = 16nt + l16, p = 32T + quad*8 + j
// Each (T,nt) PV B-fragment = contiguous 1KB, one coalesced load in attn.
__global__ void k_prep_vf(const float* __restrict__ nodes, ushort_t* __restrict__ vf) {
  int T = blockIdx.x;                   // 0..49
  int eb = blockIdx.y;                  // 0..23
  int e = eb >> 2, b = eb & 3;
  int n = e >> 1, jidx = e & 1;
  int js = jidx + (jidx >= n ? 1 : 0);
  const float* s0 = nodes + (size_t)(n * BB + b) * CC * PP;
  const float* s1 = nodes + (size_t)(js * BB + b) * CC * PP;
  ushort_t* dst = vf + ((size_t)eb * 50 + T) * 8192;
  int t = threadIdx.x;
#pragma unroll
  for (int k = 0; k < 4; ++k) {
    int cid = t + 256 * k;              // 0..1023 (16 nt x 64 lanes)
    int nt = cid >> 6, l = cid & 63;
    int quad = l >> 4, l16 = l & 15;
    int c = 16 * nt + l16;
    int p = 32 * T + quad * 8;
    const float4* a0 = (const float4*)(s0 + (size_t)c * PP + p);
    const float4* a1 = (const float4*)(s1 + (size_t)c * PP + p);
    float4 x0 = a0[0], x1 = a0[1];
    float4 y0 = a1[0], y1 = a1[1];
    short8 o;
    o[0] = (short)f2bf(x0.x + y0.x); o[1] = (short)f2bf(x0.y + y0.y);
    o[2] = (short)f2bf(x0.z + y0.z); o[3] = (short)f2bf(x0.w + y0.w);
    o[4] = (short)f2bf(x1.x + y1.x); o[5] = (short)f2bf(x1.y + y1.y);
    o[6] = (short)f2bf(x1.z + y1.z); o[7] = (short)f2bf(x1.w + y1.w);
    *(short8*)(dst + (size_t)cid * 8) = o;
  }
}

// Flash attention, 64-p block, 4 waves, swapped-S softmax.
//
// R5 post-mortem established the REAL limiter: L2/L3-level bandwidth.
// R1/R3/R4/R5 all pin at ~8-9 TB/s of cache-level traffic (R4: 2.0GB/237us,
// R5: 3.9GB/420us -- dur tracks bytes, not occupancy/barriers). So this round
// halves bytes: 64-p tiles -> 25 q-passes over ej/vf instead of 50.
//   traffic = 600 blocks x (0.82MB ej + 0.82MB vf) + th + agg ~= 1.04 GB
//   (R4: 2.03 GB). BW floor ~= 120us.
// Structure:
//  - 4 waves x 16 p-rows. SWAPPED S-GEMM: S^T = mfma(A=ej_frag, B=th_frag).
//    For 16x16x32, A and B per-lane layouts are the same mapping, so Ath and
//    the Ej LDS reads are IDENTICAL to before -- only mfma args swap. C rows
//    become q, cols become p=l16: the softmax row is now per-lane.
//  - softmax: 8 in-lane values -> 7 fmax + 2 shuffles (xor16/32) vs 32
//    shuffle ops before. M/L scalars. alpha/Linv published via tiny Al LDS.
//  - P written to shared Sp (2x ds_write_b64/lane), PV A-frags read by all
//    waves from Sp; V via frag-major vf, channel-split (wave w: ch 64w..64w+64,
//    4 coalesced 1KB loads/iter) -> each vf byte read ONCE per block.
//  - Ej (32q x 256c, 16KB) async-staged single-buffer, restage after barrier B.
//  - 2 barriers/iter kept: R4 proved they don't matter while BW-bound.
// launch_bounds(256,2): VGPR cap 256 -> zero spill risk (R2 lesson). Occupancy
// will be ~12-16% (2 blocks/CU, 512+88) -- acceptable under the BW model.
__global__ __launch_bounds__(256, 2) void k_attn_mfma(
    const ushort_t* __restrict__ nodes_bf_t,  // [12][1600][256] chunk-swizzled
    const ushort_t* __restrict__ th_t,        // [12][1600][256] plain
    const ushort_t* __restrict__ vf,          // [24][50][16][512] frag-major
    float* __restrict__ agg_t)                // [2][12][1600][256]
{
  __shared__ ushort_t Ej[32 * 256];   // 16 KB
  __shared__ ushort_t Sp[64 * 40];    // 5 KB (rows padded to 40 u16 = 80B)
  __shared__ float Al[64];
  __shared__ float Linv[64];

  const int t = threadIdx.x;
  const int w = t >> 6;               // 0..3
  const int l = t & 63;
  const int quad = l >> 4;
  const int l16 = l & 15;
  const int p0 = blockIdx.x * 64;
  const int nb = blockIdx.y;
  const int jidx = blockIdx.z;
  const int n = nb >> 2, b = nb & 3;
  const int e = n * 2 + jidx;
  const int js = jidx + (jidx >= n ? 1 : 0);
  const int eb = e * BB + b;

  const ushort_t* ejb = nodes_bf_t + ((size_t)(js * BB + b) * PP) * CC;  // [q][c-swz]
  const ushort_t* vbase = vf + (size_t)eb * 50 * 8192;

  // th B-frags for this wave's rows p = p0 + 16w + l16 (resident all 25 iters)
  short8 Ath[8];
  {
    const ushort_t* arow = th_t + ((size_t)nb * PP + p0 + 16 * w + l16) * CC + quad * 8;
#pragma unroll
    for (int ks = 0; ks < 8; ++ks) Ath[ks] = *(const short8*)(arow + ks * 32);
  }

  float M = -3.0e38f, Lr = 0.f;       // per-lane: this lane's p-row state
  f32x4 O[4][4];
#pragma unroll
  for (int mt = 0; mt < 4; ++mt)
#pragma unroll
    for (int nt = 0; nt < 4; ++nt)
#pragma unroll
      for (int r = 0; r < 4; ++r) O[mt][nt][r] = 0.f;

  // prologue: stage q-tile 0 (16 chunks of 1KB, wave w does 4)
#pragma unroll
  for (int i = 0; i < 4; ++i)
    async_ld16(ejb + (4 * w + i) * 512 + l * 8, &Ej[(4 * w + i) * 512]);

  for (int T = 0; T < 50; ++T) {
    __syncthreads();   // A: Ej[T] landed (barrier drains vmcnt); Sp/Al free
    // V frags for this iter (coalesced 1KB each); vmcnt-covered by S+softmax
    short8 Bv[4];
    {
      const ushort_t* vt = vbase + (size_t)T * 8192;
#pragma unroll
      for (int nt = 0; nt < 4; ++nt)
        Bv[nt] = *(const short8*)(vt + (4 * w + nt) * 512 + l * 8);
    }
    // ---- swapped S-GEMM: S^T[q][p], rows q = quad*4+r (+16), cols p = l16 ----
    f32x4 S0, S1;
#pragma unroll
    for (int r = 0; r < 4; ++r) { S0[r] = 0.f; S1[r] = 0.f; }
#pragma unroll
    for (int ks = 0; ks < 8; ++ks) {
      int ch0 = (((ks * 4 + quad) ^ (l16 & 7)) << 3);
      short8 A0 = *(const short8*)(Ej + l16 * CC + ch0);
      short8 A1 = *(const short8*)(Ej + (16 + l16) * CC + ch0);
      S0 = __builtin_amdgcn_mfma_f32_16x16x32_bf16(A0, Ath[ks], S0, 0, 0, 0);
      S1 = __builtin_amdgcn_mfma_f32_16x16x32_bf16(A1, Ath[ks], S1, 0, 0, 0);
    }
    // ---- softmax: 8 in-lane q-values for p = p0+16w+l16; reduce across quads ----
    float m = fmaxf(fmaxf(fmaxf(S0[0], S0[1]), fmaxf(S0[2], S0[3])),
                    fmaxf(fmaxf(S1[0], S1[1]), fmaxf(S1[2], S1[3])));
    m = fmaxf(m, __shfl_xor(m, 16));
    m = fmaxf(m, __shfl_xor(m, 32));
    float Mn = fmaxf(M, m);
    float al = __expf(M - Mn);
    float e0 = __expf(S0[0] - Mn), e1 = __expf(S0[1] - Mn);
    float e2 = __expf(S0[2] - Mn), e3 = __expf(S0[3] - Mn);
    float e4 = __expf(S1[0] - Mn), e5 = __expf(S1[1] - Mn);
    float e6 = __expf(S1[2] - Mn), e7 = __expf(S1[3] - Mn);
    float s = ((e0 + e1) + (e2 + e3)) + ((e4 + e5) + (e6 + e7));
    s += __shfl_xor(s, 16);
    s += __shfl_xor(s, 32);
    Lr = Lr * al + s;
    M = Mn;
    {
      uint2 u;
      u.x = (uint_t)f2bf(e0) | ((uint_t)f2bf(e1) << 16);
      u.y = (uint_t)f2bf(e2) | ((uint_t)f2bf(e3) << 16);
      *(uint2*)&Sp[(16 * w + l16) * 40 + quad * 4] = u;
      uint2 v;
      v.x = (uint_t)f2bf(e4) | ((uint_t)f2bf(e5) << 16);
      v.y = (uint_t)f2bf(e6) | ((uint_t)f2bf(e7) << 16);
      *(uint2*)&Sp[(16 * w + l16) * 40 + 16 + quad * 4] = v;
      if (quad == 0) Al[16 * w + l16] = al;
    }
    __syncthreads();   // B: Sp/Al visible; all waves done reading Ej
    // restage Ej for T+1 (nobody reads Ej until next A, which drains vmcnt)
    if (T < 49) {
#pragma unroll
      for (int i = 0; i < 4; ++i)
        async_ld16(ejb + (size_t)(T + 1) * 8192 + (4 * w + i) * 512 + l * 8,
                   &Ej[(4 * w + i) * 512]);
    }
    // ---- rescale O (alpha of row 16mt+quad*4+r via Al broadcast reads) ----
#pragma unroll
    for (int mt = 0; mt < 4; ++mt) {
      f32x4 a4 = *(const f32x4*)&Al[16 * mt + quad * 4];
#pragma unroll
      for (int nt = 0; nt < 4; ++nt)
#pragma unroll
        for (int r = 0; r < 4; ++r) O[mt][nt][r] *= a4[r];
    }
    // ---- PV: O[p=16mt+quad*4+r][c=64w+16nt+l16] ----
#pragma unroll
    for (int mt = 0; mt < 4; ++mt) {
      short8 Ap = *(const short8*)&Sp[(16 * mt + l16) * 40 + quad * 8];
#pragma unroll
      for (int nt = 0; nt < 4; ++nt)
        O[mt][nt] = __builtin_amdgcn_mfma_f32_16x16x32_bf16(Ap, Bv[nt], O[mt][nt], 0, 0, 0);
    }
  }
  // ---- publish 1/L, then epilogue ----
  __syncthreads();
  if (quad == 0) Linv[16 * w + l16] = 1.f / Lr;
  __syncthreads();
  float* ao = agg_t + (((size_t)jidx * NBB + nb) * PP + p0) * CC;
#pragma unroll
  for (int mt = 0; mt < 4; ++mt) {
    f32x4 li = *(const f32x4*)&Linv[16 * mt + quad * 4];
#pragma unroll
    for (int r = 0; r < 4; ++r) {
      float* dst = ao + (size_t)(16 * mt + quad * 4 + r) * CC + 64 * w + l16;
#pragma unroll
      for (int nt = 0; nt < 4; ++nt) dst[16 * nt] = O[mt][nt][r] * li[r];
    }
  }
}

// ---- conv prep ----

// reorder conv weights [M][512][3][3] fp32 -> [M][9][512] bf16
__global__ void k_wrep(const float* __restrict__ w, ushort_t* __restrict__ wr) {
  int i = blockIdx.x * 256 + threadIdx.x;   // M*9*512
  int ci = i & 511;
  int rest = i >> 9;                        // co*9 + tap
  int tp = rest % 9, co = rest / 9;
  wr[i] = f2bf(w[((size_t)co * 512 + ci) * 9 + tp]);
}

__global__ void k_pad_zero(ushort_t* __restrict__ xpad) {
  int i = blockIdx.x * 256 + threadIdx.x;   // 12*1764*512
  xpad[i] = 0;
}

// interior rows, ch 0..255 <- agg_t[0]+agg_t[1]  (both already [px][c])
__global__ void k_pad_agg(const float* __restrict__ agg_t, ushort_t* __restrict__ xpad) {
  int i = blockIdx.x * 256 + threadIdx.x;   // 12*1600*256
  int c = i & 255;
  int rest = i >> 8;
  int px = rest % PP, nb = rest / PP;
  int y = px / 40, x = px - y * 40;
  size_t src = ((size_t)nb * PP + px) * CC + c;
  float v = agg_t[src] + agg_t[(size_t)NBB * PP * CC + src];
  xpad[((size_t)nb * PAD + (y + 1) * 42 + (x + 1)) * C2 + c] = f2bf(v);
}

// interior rows, ch 256..511 <- transpose of srcA [nb][256][1600]
// MODE 0: val = h[c][px];  MODE 1: val = h[c][px] * r[c][px]
template <int MODE>
__global__ void k_pad_tr(const float* __restrict__ srcA, const float* __restrict__ srcB,
                         ushort_t* __restrict__ xpad) {
  __shared__ float tile[32][33];
  int nb = blockIdx.z;
  int c0 = blockIdx.y * 32;
  int pp0 = blockIdx.x * 32;
  int tx = threadIdx.x & 31, ty = threadIdx.x >> 5;
#pragma unroll
  for (int i = 0; i < 4; ++i) {
    int c = c0 + ty + 8 * i;
    float v = srcA[((size_t)nb * CC + c) * PP + pp0 + tx];
    if (MODE == 1) v *= srcB[((size_t)nb * C2 + c) * PP + pp0 + tx];  // r-gate
    tile[ty + 8 * i][tx] = v;
  }
  __syncthreads();
#pragma unroll
  for (int i = 0; i < 4; ++i) {
    int px = pp0 + ty + 8 * i;
    int y = px / 40, x = px - y * 40;
    xpad[((size_t)nb * PAD + (y + 1) * 42 + (x + 1)) * C2 + CC + c0 + tx] =
        f2bf(tile[tx][ty + 8 * i]);
  }
}

// Implicit-GEMM conv3x3, M=co, N=px(1600), K=9 taps x 512 ci.
// Block: 128co x 128px, 4 waves (2x2), each 64x64 (4x4 16x16x32 frags).
// ACT 0: out = sigmoid(acc+bias) -> gates [nb][512][1600]
// ACT 1: v = tanh(acc+bias); z = zsrc[256+co]; out(nodes) = (1-z)h + z*v
template <int ACT>
__global__ __launch_bounds__(256) void k_conv_mfma(
    const ushort_t* __restrict__ xpad,   // [12][1764][512]
    const ushort_t* __restrict__ wr,     // [M][9*512]
    const float* __restrict__ bias,      // [M]
    const float* __restrict__ zsrc,      // gates (ACT1)
    float* __restrict__ out)
{
  __shared__ ushort_t Asm[128 * 32];
  __shared__ ushort_t Bsm[128 * 32];
  const int t = threadIdx.x;
  const int w = t >> 6, l = t & 63, quad = l >> 4, l16 = l & 15;
  const int nb = blockIdx.z;
  const int m0 = blockIdx.y * 128;
  const int px0 = blockIdx.x * 128;
  const int wm = (w >> 1) * 64, wn = (w & 1) * 64;

  // --- staging source setup (lane l covers rows 32w + l/4 and +16) ---
  const int lr = l >> 2;
  const int swf = (lr ^ (lr >> 2)) & 3;          // fill-side XOR swizzle
  const int lk = ((l & 3) ^ swf) * 8;            // k-part (shorts)
  const ushort_t* wsrc = wr + (size_t)(m0 + 32 * w + lr) * 4608 + lk;
  int pxa = px0 + 32 * w + lr;      if (pxa > 1599) pxa = 1599;
  int pxb = pxa + 16;               if (pxb > 1599) pxb = 1599;
  {
    int d = px0 + 32 * w + 16 + lr; if (d <= 1599) pxb = d;
  }
  const int ya = pxa / 40, xa = pxa - ya * 40;
  const int yb = pxb / 40, xb = pxb - yb * 40;
  const ushort_t* bsrc_a = xpad + ((size_t)nb * PAD + ya * 42 + xa) * C2 + lk;
  const ushort_t* bsrc_b = xpad + ((size_t)nb * PAD + yb * 42 + xb) * C2 + lk;
  ushort_t* Ad0 = Asm + w * 1024;   // wave-uniform LDS base; HW adds lane*16B
  ushort_t* Ad1 = Asm + w * 1024 + 512;
  ushort_t* Bd0 = Bsm + w * 1024;
  ushort_t* Bd1 = Bsm + w * 1024 + 512;

  // --- frag-read swizzle (row&15 == l16 on both A and B) ---
  const int swr = (l16 ^ (l16 >> 2)) & 3;
  const int fk = ((quad ^ swr) * 8);

  f32x4 acc[4][4];
#pragma unroll
  for (int mt = 0; mt < 4; ++mt)
#pragma unroll
    for (int nt = 0; nt < 4; ++nt)
#pragma unroll
      for (int r = 0; r < 4; ++r) acc[mt][nt][r] = 0.f;

  for (int tap = 0; tap < 9; ++tap) {
    const int ky = tap / 3, kx = tap - ky * 3;
    const int boff = (ky * 42 + kx) * C2;
    const ushort_t* wtap = wsrc + tap * 512;
#pragma unroll 1
    for (int c0 = 0; c0 < 512; c0 += 32) {
      __syncthreads();
      async_ld16(wtap + c0, Ad0);
      async_ld16(wtap + 16 * 4608 + c0, Ad1);
      async_ld16(bsrc_a + boff + c0, Bd0);
      async_ld16(bsrc_b + boff + c0, Bd1);
      __syncthreads();
      short8 Af[4], Bf[4];
#pragma unroll
      for (int mt = 0; mt < 4; ++mt)
        Af[mt] = *(const short8*)(Asm + (wm + mt * 16 + l16) * 32 + fk);
#pragma unroll
      for (int nt = 0; nt < 4; ++nt)
        Bf[nt] = *(const short8*)(Bsm + (wn + nt * 16 + l16) * 32 + fk);
#pragma unroll
      for (int mt = 0; mt < 4; ++mt)
#pragma unroll
        for (int nt = 0; nt < 4; ++nt)
          acc[mt][nt] = __builtin_amdgcn_mfma_f32_16x16x32_bf16(Af[mt], Bf[nt], acc[mt][nt], 0, 0, 0);
    }
  }

  // --- epilogue ---
#pragma unroll
  for (int mt = 0; mt < 4; ++mt) {
#pragma unroll
    for (int r = 0; r < 4; ++r) {
      int co = m0 + wm + mt * 16 + quad * 4 + r;
      float bv = bias[co];
#pragma unroll
      for (int nt = 0; nt < 4; ++nt) {
        int px = px0 + wn + nt * 16 + l16;
        if (px >= PP) continue;
        float v = acc[mt][nt][r] + bv;
        if (ACT == 0) {
          out[((size_t)nb * C2 + co) * PP + px] = 1.f / (1.f + __expf(-v));
        } else {
          v = tanhf(v);
          float z = zsrc[((size_t)nb * C2 + CC + co) * PP + px];
          float* hp = out + ((size_t)nb * CC + co) * PP + px;
          float h = *hp;
          *hp = (1.f - z) * h + z * v;
        }
      }
    }
  }
}

extern "C" void kernel_launch(void* const* d_in, const int* in_sizes, int n_in,
                              void* d_out, int out_size, void* d_ws, size_t ws_size,
                              hipStream_t stream) {
  const float* nodes_in = (const float*)d_in[0];
  const float* tw = (const float*)d_in[1];
  const float* tb = (const float*)d_in[2];
  const float* gw = (const float*)d_in[3];
  const float* gb = (const float*)d_in[4];
  const float* cw = (const float*)d_in[5];
  const float* cb = (const float*)d_in[6];

  float* nodes = (float*)d_out;                      // fp32 state [12][256][1600]
  char* ws = (char*)d_ws;
  // ---- layout (ws >= 98.3 MB) ----
  // attn phase: R0 nodes_bf_t 9.83 | R1 th_t 9.83 | R2 vf 19.66 | R3 agg_t 39.32
  // conv phase: R1+R2 xh_pad 21.68 | R3 gates 39.32
  // persistent:  78.64.. w_g_r 4.72 | 83.36.. w_c_r 2.36   (pass-invariant)
  ushort_t* nodes_bf_t = (ushort_t*)ws;
  ushort_t* th_t  = (ushort_t*)(ws + 9830400);
  ushort_t* vf    = (ushort_t*)(ws + 19660800);
  float*    agg_t = (float*)(ws + 39321600);
  ushort_t* xh_pad = (ushort_t*)(ws + 9830400);      // 12*1764*512*2 = 21,676,032
  float*    gates = (float*)(ws + 39321600);
  ushort_t* w_g_r = (ushort_t*)(ws + 78643200);      // 4,718,592 B
  ushort_t* w_c_r = (ushort_t*)(ws + 83361792);      // 2,359,296 B (ends 85.7 MB)

  k_copy<<<NODESZ / 256, 256, 0, stream>>>(nodes_in, nodes);
  k_wrep<<<(C2 * 9 * C2) / 256, 256, 0, stream>>>(gw, w_g_r);
  k_wrep<<<(CC * 9 * C2) / 256, 256, 0, stream>>>(cw, w_c_r);
  for (int pass = 0; pass < 2; ++pass) {
    // ---- attention ----
    k_theta<<<dim3(5, NBB * (CC / TO)), 320, 0, stream>>>(nodes, tw, tb, th_t);
    k_to_bf_t<<<dim3(50, 8, NBB), 256, 0, stream>>>(nodes, nodes_bf_t);
    k_prep_vf<<<dim3(50, 24), 256, 0, stream>>>(nodes, vf);
    k_attn_mfma<<<dim3(25, NBB, 2), 256, 0, stream>>>(nodes_bf_t, th_t, vf, agg_t);
    // ---- conv prep (attn scratch now dead) ----
    k_pad_zero<<<(NBB * PAD * C2) / 256, 256, 0, stream>>>(xh_pad);
    k_pad_agg<<<(NBB * PP * CC) / 256, 256, 0, stream>>>(agg_t, xh_pad);
    k_pad_tr<0><<<dim3(50, 8, NBB), 256, 0, stream>>>(nodes, nullptr, xh_pad);
    // ---- gates conv ----
    k_conv_mfma<0><<<dim3(13, 4, NBB), 256, 0, stream>>>(xh_pad, w_g_r, gb, nullptr, gates);
    // ---- r*h into xh_pad high channels ----
    k_pad_tr<1><<<dim3(50, 8, NBB), 256, 0, stream>>>(nodes, gates, xh_pad);
    // ---- cand conv + fused GRU update ----
    k_conv_mfma<1><<<dim3(13, 2, NBB), 256, 0, stream>>>(xh_pad, w_c_r, cb, gates, nodes);
  }
}